// Round 4
// baseline (429.848 us; speedup 1.0000x reference)
//
#include <hip/hip_runtime.h>
#include <hip/hip_fp16.h>

// GraphEmbedding2: 3-layer GCN (DGL GraphConv, norm='both') + per-graph mean pooling.
// N=50000 nodes, E=600000 edges, d=128, G=64 graphs.
// fp16 gather operands (R6); LDS-histogram degrees + LDS-cursor CSR fill (R5/R8);
// MFMA fp16-in/fp32-acc transposed roles (R9/R15); pool-fused layer 3 (R15);
// HIST_S=64 (R14).
// R18: QUARTERED GATHER. R17 (halved agg VMEM instrs) was exactly neutral -> agg is
// memory-system-bound, not issue-bound. R16 PMC: FETCH 56.8MB/layer vs 15MB unique
// (3.7x HBM refetch) at 685 GB/s -> the 12.8MB gather table doesn't fit per-XCD L2
// (4MB) and re-reads stream from LLC/HBM. Fix: feature dim split into 4 CONTIGUOUS
// 3.2MB quarter-tables (A_q[q][node][32feats]); agg runs as 4 dispatches/layer, each
// gathering one L2-resident quarter (cold-fill once, ~11x re-reads at L2 BW).
// prep/gemm produce quarter-major at no extra cost; gemm b[q] fragment = quarter q.
// Reverted-for-cause: R7/R16 fusion (lost gather parallelism), R11 range passes,
// R13 HIST_S=32 (grid coverage), R17 32-edge-round shape (neutral, superseded).

#define DIM 128
#define GRAPHS 64

typedef _Float16 half8 __attribute__((ext_vector_type(8)));
typedef _Float16 half4 __attribute__((ext_vector_type(4)));
typedef float floatx4 __attribute__((ext_vector_type(4)));

// ---------------------------------------------------------------- degree histogram (LDS)
#define HIST_R 4
#define HIST_S 64
#define NPR 12500          // nodes per range (HIST_R * NPR = 50000)
#define LDSW (NPR / 2)     // 6250 u32 words, 25 KB LDS

__global__ __launch_bounds__(256) void k_hist(const int* __restrict__ src,
                                              const int* __restrict__ dst,
                                              unsigned* __restrict__ partial, int E) {
    __shared__ unsigned hist[LDSW];
    int b = blockIdx.x;
    int a = b / (HIST_R * HIST_S);       // 0: src, 1: dst
    int r = (b / HIST_S) % HIST_R;       // node range
    int s = b % HIST_S;                  // edge slice
    const int* arr = a ? dst : src;
    for (int i = threadIdx.x; i < LDSW; i += 256) hist[i] = 0;
    __syncthreads();
    int chunk = (E + HIST_S - 1) / HIST_S;
    int e0 = s * chunk;
    int e1 = min(e0 + chunk, E);
    unsigned base = (unsigned)(r * NPR);
    for (int i = e0 + threadIdx.x; i < e1; i += 256) {
        unsigned n = (unsigned)arr[i] - base;
        if (n < NPR) atomicAdd(&hist[n >> 1], 1u << ((n & 1) * 16));
    }
    __syncthreads();
    unsigned* outp = partial + ((size_t)(a * HIST_R + r) * HIST_S + s) * LDSW;
    for (int i = threadIdx.x; i < LDSW; i += 256) outp[i] = hist[i];
}

// ---------------------------------------------------------------- merge + block sums
__global__ __launch_bounds__(256) void k_hist_merge(const unsigned* __restrict__ partial,
                                                    float* __restrict__ ns,
                                                    float* __restrict__ nd,
                                                    int* __restrict__ inc,
                                                    int* __restrict__ bsum, int N) {
    __shared__ int sred[256];
    int nb = (N + 255) / 256;
    int isDst = (blockIdx.x < nb) ? 1 : 0;
    int cb = isDst ? blockIdx.x : blockIdx.x - nb;
    int n = cb * 256 + threadIdx.x;
    int deg = 0;
    if (n < N) {
        int a = isDst ? 1 : 0;
        int r = n / NPR;
        int w = (n % NPR) >> 1;
        int field = (n & 1) * 16;
        const unsigned* p = partial + ((size_t)(a * HIST_R + r) * HIST_S) * LDSW + w;
        unsigned sum = 0;
#pragma unroll
        for (int s = 0; s < HIST_S; ++s) sum += p[(size_t)s * LDSW];
        deg = (int)((sum >> field) & 0xFFFFu);
        float nrm = rsqrtf(fmaxf((float)deg, 1.0f));
        if (isDst) { nd[n] = nrm; inc[n] = deg; }
        else       { ns[n] = nrm; }
    }
    if (isDst) {
        sred[threadIdx.x] = deg;
        __syncthreads();
        for (int off = 128; off > 0; off >>= 1) {
            if (threadIdx.x < off) sred[threadIdx.x] += sred[threadIdx.x + off];
            __syncthreads();
        }
        if (threadIdx.x == 0) bsum[cb] = sred[0];
    }
}

// ---------------------------------------------------------------- scan_write + cursor
__global__ __launch_bounds__(256) void k_scan_write(const int* __restrict__ inc,
                                                    const int* __restrict__ bsum,
                                                    const unsigned* __restrict__ partial,
                                                    int* __restrict__ row_ptr,
                                                    int* __restrict__ cur,
                                                    float* __restrict__ gsum, int N) {
    __shared__ int sb[256];
    __shared__ int s[256];
    __shared__ int exs[256];
    int nb = (N + 255) / 256;
    int t = threadIdx.x;

    // phase 0: exclusive-scan block sums
    int bv = (t < nb) ? bsum[t] : 0;
    sb[t] = bv;
    __syncthreads();
    for (int off = 1; off < 256; off <<= 1) {
        int u = (t >= off) ? sb[t - off] : 0;
        __syncthreads();
        sb[t] += u;
        __syncthreads();
    }
    int excl = sb[t] - bv;
    __syncthreads();
    sb[t] = excl;
    __syncthreads();
    int blockBase = sb[blockIdx.x];

    // phase A: local scan of inc
    int B = blockIdx.x * 256;
    int i = B + t;
    int v = (i < N) ? inc[i] : 0;
    s[t] = v;
    __syncthreads();
    for (int off = 1; off < 256; off <<= 1) {
        int u = (t >= off) ? s[t - off] : 0;
        __syncthreads();
        s[t] += u;
        __syncthreads();
    }
    int ex = blockBase + s[t] - v;  // global exclusive prefix
    exs[t] = ex;
    if (i < N) row_ptr[i] = ex;
    if (i == N - 1) row_ptr[N] = ex + v;
    if (blockIdx.x == 0) {
        for (int j = t; j < GRAPHS * DIM; j += 256) gsum[j] = 0.0f;
    }
    __syncthreads();

    // phase B: per-slice cursors
    if (t < 128) {
        int n0 = B + 2 * t;
        if (n0 < N) {
            int r = n0 / NPR;
            int w = (n0 % NPR) >> 1;
            const unsigned* p = partial + ((size_t)(HIST_R + r) * HIST_S) * LDSW + w;
            int run0 = exs[2 * t];
            int run1 = exs[2 * t + 1];
            int* c = cur + (size_t)r * HIST_S * NPR + 2 * w;
#pragma unroll
            for (int sl = 0; sl < HIST_S; ++sl) {
                c[(size_t)sl * NPR + 0] = run0;
                c[(size_t)sl * NPR + 1] = run1;
                unsigned hv = p[(size_t)sl * LDSW];
                run0 += (int)(hv & 0xFFFFu);
                run1 += (int)(hv >> 16);
            }
        }
    }
}

// ---------------------------------------------------------------- CSR fill (LDS cursors)
__global__ __launch_bounds__(256) void k_fill2(const int* __restrict__ src,
                                               const int* __restrict__ dst,
                                               const int* __restrict__ cur,
                                               int* __restrict__ csr, int E) {
    __shared__ int lcur[NPR];   // 50 KB
    int r = blockIdx.x / HIST_S;
    int s = blockIdx.x % HIST_S;
    const int* cs = cur + (size_t)(r * HIST_S + s) * NPR;
    for (int i = threadIdx.x; i < NPR; i += 256) lcur[i] = cs[i];
    __syncthreads();
    int chunk = (E + HIST_S - 1) / HIST_S;
    int e0 = s * chunk;
    int e1 = min(e0 + chunk, E);
    unsigned base = (unsigned)(r * NPR);
    for (int i = e0 + threadIdx.x; i < e1; i += 256) {
        unsigned d = (unsigned)dst[i] - base;
        if (d < NPR) {
            int p = atomicAdd(&lcur[d], 1);   // LDS atomic
            csr[p] = src[i];
        }
    }
}

// ---------------------------------------------------------------- prep: h->fp16(h*ns) quarters, W^T
// Quarter-major operand: A_q[q][node][32 feats], quarter stride QSU2 = N*8 (uint2 units).
__global__ void k_prep(const float4* __restrict__ h, const float* __restrict__ ns,
                       uint2* __restrict__ A,
                       const float* __restrict__ W1, const float* __restrict__ W2,
                       const float* __restrict__ W3, _Float16* __restrict__ Wt1,
                       _Float16* __restrict__ Wt2, _Float16* __restrict__ Wt3, int N) {
    int i = blockIdx.x * blockDim.x + threadIdx.x;
    int nf4 = N * 32;
    if (i < nf4) {
        int n = i >> 5;
        int f4 = i & 31;               // 4-feat group 0..31
        float s = ns[n];
        float4 v = h[i];
        __half2 p0 = __floats2half2_rn(v.x * s, v.y * s);
        __half2 p1 = __floats2half2_rn(v.z * s, v.w * s);
        uint2 o;
        o.x = *(unsigned*)&p0;
        o.y = *(unsigned*)&p1;
        int q = f4 >> 3;               // quarter
        int slot = f4 & 7;             // 8B slot within 64B quarter-row
        A[(size_t)q * N * 8 + (size_t)n * 8 + slot] = o;
    } else {
        int j = i - nf4;               // 0 .. 3*16384-1
        if (j < 3 * 16384) {
            int which = j >> 14;
            int local = j & 16383;
            int k = local >> 7;
            int n = local & 127;
            const float* W = (which == 0) ? W1 : (which == 1) ? W2 : W3;
            _Float16* Wt = (which == 0) ? Wt1 : (which == 1) ? Wt2 : Wt3;
            Wt[(size_t)n * DIM + k] = (_Float16)W[local];
        }
    }
}

// ---------------------------------------------------------------- aggregation (R18: one quarter)
// One wave per node; gathers ONE 3.2MB quarter-table (L2-resident). grp=lane>>3 picks
// edge slot base+4j... slot = 8*j+grp; l8=lane&7 is the 8B slot in the 64B quarter-row
// -> one load instr covers 8 rows, 4 loads = 32 edges in flight. Indices: 1 VMEM load
// of 32 idx by lane&31 + shfl broadcast. Epilogue: shfl_xor(8/16/32) cross-group
// reduce, lanes 0-7 store one uint2 (64B/node contiguous).
__global__ __launch_bounds__(256) void k_agg(const uint2* __restrict__ Aq,
                                             const int* __restrict__ row_ptr,
                                             const int* __restrict__ csr,
                                             const float* __restrict__ nd,
                                             uint2* __restrict__ Bq, int N) {
    int gtid = blockIdx.x * blockDim.x + threadIdx.x;
    int node = gtid >> 6;
    int lane = threadIdx.x & 63;
    if (node >= N) return;
    int e0 = row_ptr[node];
    int e1 = row_ptr[node + 1];
    int grp = lane >> 3;     // edge sub-slot group (8 rows per load instr)
    int l8 = lane & 7;       // 8B slot within 64B quarter-row
    float a0 = 0.f, a1 = 0.f, a2 = 0.f, a3 = 0.f;

    for (int base = e0; base < e1; base += 32) {
        int vl = csr[min(base + (lane & 31), e1 - 1)];   // lanes 0-31 hold 32 indices
        uint2 u[4];
#pragma unroll
        for (int j = 0; j < 4; ++j) {
            int idx = __shfl(vl, 8 * j + grp);
            u[j] = Aq[(size_t)idx * 8 + l8];
        }
#pragma unroll
        for (int j = 0; j < 4; ++j) {
            if (base + 8 * j + grp < e1) {
                __half2 h0 = *(__half2*)&u[j].x;
                __half2 h1 = *(__half2*)&u[j].y;
                float2 f0 = __half22float2(h0);
                float2 f1 = __half22float2(h1);
                a0 += f0.x; a1 += f0.y; a2 += f1.x; a3 += f1.y;
            }
        }
    }

    a0 += __shfl_xor(a0, 8);  a0 += __shfl_xor(a0, 16); a0 += __shfl_xor(a0, 32);
    a1 += __shfl_xor(a1, 8);  a1 += __shfl_xor(a1, 16); a1 += __shfl_xor(a1, 32);
    a2 += __shfl_xor(a2, 8);  a2 += __shfl_xor(a2, 16); a2 += __shfl_xor(a2, 32);
    a3 += __shfl_xor(a3, 8);  a3 += __shfl_xor(a3, 16); a3 += __shfl_xor(a3, 32);

    if (grp == 0) {
        float s = nd[node];
        __half2 p0 = __floats2half2_rn(a0 * s, a1 * s);
        __half2 p1 = __floats2half2_rn(a2 * s, a3 * s);
        uint2 o;
        o.x = *(unsigned*)&p0;
        o.y = *(unsigned*)&p1;
        Bq[(size_t)node * 8 + l8] = o;
    }
}

// ---------------------------------------------------------------- GEMM (transposed roles, quarter IO)
// X[node][f] = relu(Bin[node][:] @ W + b)[f].  Bin/Xout are quarter-major (QS = N*32
// _Float16 per quarter). b[q] fragment (feats q*32+quad*8..+8) lives entirely in
// quarter q. Output feats c*16+quad*4..+4 live in quarter (c*16+quad*4)>>5.
template <bool SCALE_NS>
__global__ __launch_bounds__(256) void k_gemm_t(
    const _Float16* __restrict__ Bin, const _Float16* __restrict__ Wt,
    const float* __restrict__ bias, const float* __restrict__ ns,
    _Float16* __restrict__ Xout, int N) {
    int tid = threadIdx.x;
    int wave = tid >> 6;
    int lane = tid & 63;
    int quad = lane >> 4;
    int l16 = lane & 15;
    int node = blockIdx.x * 64 + wave * 16 + l16;
    size_t QS = (size_t)N * 32;

    half8 b[4];
#pragma unroll
    for (int q = 0; q < 4; ++q) {
        if (node < N) {
            b[q] = *(const half8*)&Bin[q * QS + (size_t)node * 32 + quad * 8];
        } else {
            b[q] = half8{0, 0, 0, 0, 0, 0, 0, 0};
        }
    }

    floatx4 acc[8];
#pragma unroll
    for (int c = 0; c < 8; ++c) acc[c] = floatx4{0.f, 0.f, 0.f, 0.f};

#pragma unroll
    for (int c = 0; c < 8; ++c) {
#pragma unroll
        for (int q = 0; q < 4; ++q) {
            half8 a = *(const half8*)&Wt[(size_t)(c * 16 + l16) * DIM + q * 32 + quad * 8];
            acc[c] = __builtin_amdgcn_mfma_f32_16x16x32_f16(a, b[q], acc[c], 0, 0, 0);
        }
    }

    if (node < N) {
        float s = SCALE_NS ? ns[node] : 1.0f;
#pragma unroll
        for (int c = 0; c < 8; ++c) {
            float4 b4 = *(const float4*)&bias[c * 16 + quad * 4];
            half4 o;
            o[0] = (_Float16)(fmaxf(acc[c][0] + b4.x, 0.0f) * s);
            o[1] = (_Float16)(fmaxf(acc[c][1] + b4.y, 0.0f) * s);
            o[2] = (_Float16)(fmaxf(acc[c][2] + b4.z, 0.0f) * s);
            o[3] = (_Float16)(fmaxf(acc[c][3] + b4.w, 0.0f) * s);
            int f0 = c * 16 + quad * 4;
            *(half4*)&Xout[(f0 >> 5) * QS + (size_t)node * 32 + (f0 & 31)] = o;
        }
    }
}

// ---------------------------------------------------------------- layer-3 GEMM fused with pooling
#define PBINS 8
__global__ __launch_bounds__(256) void k_gemm_pool(
    const _Float16* __restrict__ Bin, const _Float16* __restrict__ Wt,
    const float* __restrict__ bias, const int* __restrict__ gid,
    float* __restrict__ gsum, int N) {
    __shared__ float lsum[PBINS * DIM];   // 4 KB
    int tid = threadIdx.x;
    for (int i = tid; i < PBINS * DIM; i += 256) lsum[i] = 0.0f;
    int wave = tid >> 6;
    int lane = tid & 63;
    int quad = lane >> 4;
    int l16 = lane & 15;
    int r0 = blockIdx.x * 64;
    int node = r0 + wave * 16 + l16;
    int nodec = min(node, N - 1);
    size_t QS = (size_t)N * 32;

    half8 b[4];
#pragma unroll
    for (int q = 0; q < 4; ++q) {
        if (node < N) {
            b[q] = *(const half8*)&Bin[q * QS + (size_t)node * 32 + quad * 8];
        } else {
            b[q] = half8{0, 0, 0, 0, 0, 0, 0, 0};
        }
    }

    floatx4 acc[8];
#pragma unroll
    for (int c = 0; c < 8; ++c) acc[c] = floatx4{0.f, 0.f, 0.f, 0.f};
    __syncthreads();   // lsum zeros visible before any atomic below

#pragma unroll
    for (int c = 0; c < 8; ++c) {
#pragma unroll
        for (int q = 0; q < 4; ++q) {
            half8 a = *(const half8*)&Wt[(size_t)(c * 16 + l16) * DIM + q * 32 + quad * 8];
            acc[c] = __builtin_amdgcn_mfma_f32_16x16x32_f16(a, b[q], acc[c], 0, 0, 0);
        }
    }

    int g = gid[nodec];
    int g0b = gid[r0];                          // r0 < N for every block
    int gEb = gid[min(r0 + 63, N - 1)];
    bool ldsPath = (gEb - g0b) < PBINS;         // block spans < PBINS graphs
    int gF = __shfl(g, 0);                      // graph of wave-tile node 0
    int gL = __shfl(g, 15);                     // graph of wave-tile node 15
    bool uni = (gF == gL);                      // wave-uniform
    float valid = (node < N) ? 1.0f : 0.0f;     // zero padded-node contribution

#pragma unroll
    for (int c = 0; c < 8; ++c) {
        float4 b4 = *(const float4*)&bias[c * 16 + quad * 4];
        float bv[4] = {b4.x, b4.y, b4.z, b4.w};
#pragma unroll
        for (int r = 0; r < 4; ++r) {
            float v = fmaxf(acc[c][r] + bv[r], 0.0f) * valid;
            int f = c * 16 + quad * 4 + r;
            if (ldsPath) {
                if (uni) {
                    v += __shfl_xor(v, 1);
                    v += __shfl_xor(v, 2);
                    v += __shfl_xor(v, 4);
                    v += __shfl_xor(v, 8);      // sum over the 16 nodes of the tile
                    if (l16 == 0) atomicAdd(&lsum[(gF - g0b) * DIM + f], v);
                } else {
                    if (node < N) atomicAdd(&lsum[(g - g0b) * DIM + f], v);
                }
            } else {
                if (node < N) atomicAdd(&gsum[(size_t)g * DIM + f], v);
            }
        }
    }
    __syncthreads();
    if (ldsPath) {
        int ng = gEb - g0b + 1;
        for (int i = tid; i < ng * DIM; i += 256) {
            float sv = lsum[i];
            if (sv != 0.0f) atomicAdd(&gsum[(size_t)g0b * DIM + i], sv);
        }
    }
}

// ---------------------------------------------------------------- finalize (count via binary search)
__global__ void k_finalize(const float* __restrict__ gsum, const int* __restrict__ gid,
                           float* __restrict__ out, int N, int G) {
    int i = blockIdx.x * blockDim.x + threadIdx.x;
    if (i < G * DIM) {
        int g = i >> 7;
        int lo = 0, hi = N;                 // lower_bound(g)
        while (lo < hi) { int m = (lo + hi) >> 1; if (gid[m] < g) lo = m + 1; else hi = m; }
        int lo2 = lo, hi2 = N;              // lower_bound(g+1)
        while (lo2 < hi2) { int m = (lo2 + hi2) >> 1; if (gid[m] < g + 1) lo2 = m + 1; else hi2 = m; }
        float c = fmaxf((float)(lo2 - lo), 1.0f);
        out[i] = gsum[i] / c;
    }
}

// ---------------------------------------------------------------- launch
extern "C" void kernel_launch(void* const* d_in, const int* in_sizes, int n_in,
                              void* d_out, int out_size, void* d_ws, size_t ws_size,
                              hipStream_t stream) {
    const float* h   = (const float*)d_in[0];
    const int*   src = (const int*)d_in[1];
    const int*   dst = (const int*)d_in[2];
    const int*   gid = (const int*)d_in[3];
    const float* W1  = (const float*)d_in[4];
    const float* b1  = (const float*)d_in[5];
    const float* W2  = (const float*)d_in[6];
    const float* b2  = (const float*)d_in[7];
    const float* W3  = (const float*)d_in[8];
    const float* b3  = (const float*)d_in[9];

    const int N = in_sizes[0] / DIM;   // 50000
    const int E = in_sizes[1];         // 600000
    const int G = GRAPHS;
    float* out = (float*)d_out;

    char* ws = (char*)d_ws;
    size_t off = 0;
    auto alloc = [&](size_t bytes) -> void* {
        void* p = ws + off;
        off += (bytes + 255) & ~(size_t)255;
        return p;
    };
    const int nb = (N + 255) / 256;    // 196
    uint2* Ah0     = (uint2*)alloc((size_t)N * DIM * 2);  // fp16 gather operand (ping), quarter-major
    uint2* Ah1     = (uint2*)alloc((size_t)N * DIM * 2);  // fp16 pong, quarter-major
    uint2* Bh      = (uint2*)alloc((size_t)N * DIM * 2);  // agg output (fp16), quarter-major
    _Float16* Wt1  = (_Float16*)alloc((size_t)DIM * DIM * 2);
    _Float16* Wt2  = (_Float16*)alloc((size_t)DIM * DIM * 2);
    _Float16* Wt3  = (_Float16*)alloc((size_t)DIM * DIM * 2);
    float* ns      = (float*)alloc((size_t)N * 4);
    float* nd      = (float*)alloc((size_t)N * 4);
    int*   inc     = (int*)alloc((size_t)N * 4);
    unsigned* partial = (unsigned*)alloc((size_t)2 * HIST_R * HIST_S * LDSW * 4);  // 12.8 MB
    int*   cur     = (int*)alloc((size_t)HIST_R * HIST_S * NPR * 4);               // 12.8 MB
    int*   row_ptr = (int*)alloc((size_t)(N + 1) * 4);
    int*   csr     = (int*)alloc((size_t)E * 4);
    float* gsum    = (float*)alloc((size_t)G * DIM * 4);
    int*   bsum    = (int*)alloc((size_t)nb * 4);

    // degrees via LDS histograms (no global atomics)
    k_hist<<<2 * HIST_R * HIST_S, 256, 0, stream>>>(src, dst, partial, E);
    // merge -> ns/nd/inc + per-block sums
    k_hist_merge<<<2 * nb, 256, 0, stream>>>(partial, ns, nd, inc, bsum, N);
    // row_ptr + per-(range,slice) cursors + gsum zero
    k_scan_write<<<nb, 256, 0, stream>>>(inc, bsum, partial, row_ptr, cur, gsum, N);
    k_fill2<<<HIST_R * HIST_S, 256, 0, stream>>>(src, dst, cur, csr, E);

    // Ah0 = fp16(h*ns) quarter-major + weights -> fp16 transposed (single launch)
    int prepThreads = N * 32 + 3 * 16384;
    k_prep<<<(prepThreads + 255) / 256, 256, 0, stream>>>((const float4*)h, ns, Ah0,
                                                          W1, W2, W3, Wt1, Wt2, Wt3, N);

    int aggBlocks  = (N * 64 + 255) / 256;   // 12500
    int gemmBlocks = (N + 63) / 64;
    size_t QU2 = (size_t)N * 8;              // quarter stride in uint2 units

    // layer 1: 4 quarter-gathers (each table 3.2MB, L2-resident), then GEMM
    for (int q = 0; q < 4; ++q)
        k_agg<<<aggBlocks, 256, 0, stream>>>(Ah0 + q * QU2, row_ptr, csr, nd, Bh + q * QU2, N);
    k_gemm_t<true><<<gemmBlocks, 256, 0, stream>>>((const _Float16*)Bh, Wt1, b1, ns, (_Float16*)Ah1, N);
    // layer 2
    for (int q = 0; q < 4; ++q)
        k_agg<<<aggBlocks, 256, 0, stream>>>(Ah1 + q * QU2, row_ptr, csr, nd, Bh + q * QU2, N);
    k_gemm_t<true><<<gemmBlocks, 256, 0, stream>>>((const _Float16*)Bh, Wt2, b2, ns, (_Float16*)Ah0, N);
    // layer 3: quarter-gathers + GEMM fused with pooling
    for (int q = 0; q < 4; ++q)
        k_agg<<<aggBlocks, 256, 0, stream>>>(Ah0 + q * QU2, row_ptr, csr, nd, Bh + q * QU2, N);
    k_gemm_pool<<<gemmBlocks, 256, 0, stream>>>((const _Float16*)Bh, Wt3, b3, gid, gsum, N);

    k_finalize<<<(G * DIM + 255) / 256, 256, 0, stream>>>(gsum, gid, out, N, G);
}

// Round 5
// 347.309 us; speedup vs baseline: 1.2377x; 1.2377x over previous
//
#include <hip/hip_runtime.h>
#include <hip/hip_fp16.h>

// GraphEmbedding2: 3-layer GCN (DGL GraphConv, norm='both') + per-graph mean pooling.
// N=50000 nodes, E=600000 edges, d=128, G=64 graphs.
// fp16 gather operands (R6); MFMA fp16-in/fp32-acc transposed roles (R9/R15);
// pool-fused layer 3 + binary-search counts (R15); 32-edge-round agg (R17).
// R19: REVERT R18 quartering (FAILED +120us: per-XCD quarter reuse only 1.5x before
// cold-refill -> fabric bytes unchanged, pure overhead added). Agg is pinned by
// scattered 64B L2-miss service on a 12.8MB random table (R16/R17/R18 triangulate:
// not issue-bound, not chain-bound, not sliceable). Attack the CSR-build prologue
// instead: the LDS-histogram/cursor pipeline (R5/R8) hauled ~50MB of partial+cursor
// traffic to build a 2.4MB CSR. Replaced with direct atomic build: k_deg (2 global
// atomics/edge on L2-resident 400KB counters), k_bsum (ns/nd + block sums), k_scan
// (row_ptr + cursor init + gsum zero), k_fill (atomicAdd cursor + scatter). CSR edge
// order becomes nondeterministic; sum-order robustness proven by R15 atomic pooling.
// Reverted-for-cause: R7/R16 fusion (lost gather parallelism), R11 range passes,
// R18 quartered gather (cold-fill >= reuse).

#define DIM 128
#define GRAPHS 64

typedef _Float16 half8 __attribute__((ext_vector_type(8)));
typedef _Float16 half4 __attribute__((ext_vector_type(4)));
typedef float floatx4 __attribute__((ext_vector_type(4)));

// ---------------------------------------------------------------- degrees (global atomics)
__global__ __launch_bounds__(256) void k_deg(const int* __restrict__ src,
                                             const int* __restrict__ dst,
                                             int* __restrict__ degs,
                                             int* __restrict__ degd, int E) {
    int e = blockIdx.x * 256 + threadIdx.x;
    if (e < E) {
        atomicAdd(&degs[src[e]], 1);
        atomicAdd(&degd[dst[e]], 1);
    }
}

// ---------------------------------------------------------------- ns/nd + per-256 block sums
// Blocks [0, nb): dst — nd + bsum. Blocks [nb, 2nb): src — ns.
__global__ __launch_bounds__(256) void k_bsum(const int* __restrict__ degs,
                                              const int* __restrict__ degd,
                                              float* __restrict__ ns,
                                              float* __restrict__ nd,
                                              int* __restrict__ bsum, int N) {
    __shared__ int sred[256];
    int nb = (N + 255) / 256;
    int isDst = (blockIdx.x < nb) ? 1 : 0;
    int cb = isDst ? blockIdx.x : blockIdx.x - nb;
    int n = cb * 256 + threadIdx.x;
    int deg = 0;
    if (n < N) {
        deg = isDst ? degd[n] : degs[n];
        float nrm = rsqrtf(fmaxf((float)deg, 1.0f));
        if (isDst) nd[n] = nrm; else ns[n] = nrm;
    }
    if (isDst) {
        sred[threadIdx.x] = deg;
        __syncthreads();
        for (int off = 128; off > 0; off >>= 1) {
            if (threadIdx.x < off) sred[threadIdx.x] += sred[threadIdx.x + off];
            __syncthreads();
        }
        if (threadIdx.x == 0) bsum[cb] = sred[0];
    }
}

// ---------------------------------------------------------------- scan -> row_ptr + cursor
// Phase 0: every block scans the nb (<256) block sums in LDS -> its global base.
// Phase A: block-local scan of degd -> row_ptr + cursor copy. Block 0 zeroes gsum.
__global__ __launch_bounds__(256) void k_scan(const int* __restrict__ degd,
                                              const int* __restrict__ bsum,
                                              int* __restrict__ row_ptr,
                                              int* __restrict__ cursor,
                                              float* __restrict__ gsum, int N) {
    __shared__ int sb[256];
    __shared__ int s[256];
    int nb = (N + 255) / 256;
    int t = threadIdx.x;

    int bv = (t < nb) ? bsum[t] : 0;
    sb[t] = bv;
    __syncthreads();
    for (int off = 1; off < 256; off <<= 1) {
        int u = (t >= off) ? sb[t - off] : 0;
        __syncthreads();
        sb[t] += u;
        __syncthreads();
    }
    int excl = sb[t] - bv;
    __syncthreads();
    sb[t] = excl;
    __syncthreads();
    int blockBase = sb[blockIdx.x];

    int B = blockIdx.x * 256;
    int i = B + t;
    int v = (i < N) ? degd[i] : 0;
    s[t] = v;
    __syncthreads();
    for (int off = 1; off < 256; off <<= 1) {
        int u = (t >= off) ? s[t - off] : 0;
        __syncthreads();
        s[t] += u;
        __syncthreads();
    }
    int ex = blockBase + s[t] - v;  // global exclusive prefix
    if (i < N) { row_ptr[i] = ex; cursor[i] = ex; }
    if (i == N - 1) row_ptr[N] = ex + v;
    if (blockIdx.x == 0) {
        for (int j = t; j < GRAPHS * DIM; j += 256) gsum[j] = 0.0f;
    }
}

// ---------------------------------------------------------------- CSR fill (global atomic cursor)
__global__ __launch_bounds__(256) void k_fill(const int* __restrict__ src,
                                              const int* __restrict__ dst,
                                              int* __restrict__ cursor,
                                              int* __restrict__ csr, int E) {
    int e = blockIdx.x * 256 + threadIdx.x;
    if (e < E) {
        int d = dst[e];
        int p = atomicAdd(&cursor[d], 1);
        csr[p] = src[e];
    }
}

// ---------------------------------------------------------------- prep: h->fp16(h*ns), W1..3->fp16^T
__global__ void k_prep(const float4* __restrict__ h, const float* __restrict__ ns,
                       uint2* __restrict__ A,
                       const float* __restrict__ W1, const float* __restrict__ W2,
                       const float* __restrict__ W3, _Float16* __restrict__ Wt1,
                       _Float16* __restrict__ Wt2, _Float16* __restrict__ Wt3, int N) {
    int i = blockIdx.x * blockDim.x + threadIdx.x;
    int nf4 = N * 32;
    if (i < nf4) {
        int n = i >> 5;
        float s = ns[n];
        float4 v = h[i];
        __half2 p0 = __floats2half2_rn(v.x * s, v.y * s);
        __half2 p1 = __floats2half2_rn(v.z * s, v.w * s);
        uint2 o;
        o.x = *(unsigned*)&p0;
        o.y = *(unsigned*)&p1;
        A[i] = o;
    } else {
        int j = i - nf4;               // 0 .. 3*16384-1
        if (j < 3 * 16384) {
            int which = j >> 14;
            int local = j & 16383;
            int k = local >> 7;
            int n = local & 127;
            const float* W = (which == 0) ? W1 : (which == 1) ? W2 : W3;
            _Float16* Wt = (which == 0) ? Wt1 : (which == 1) ? Wt2 : Wt3;
            Wt[(size_t)n * DIM + k] = (_Float16)W[local];
        }
    }
}

// ---------------------------------------------------------------- aggregation (R17 form)
// One wave per node (50K waves). 32-edge rounds: group = lane>>4 picks edge slot
// base+4j+grp, 16 lanes x 16B cover one 256B row -> 4 rows per load instruction,
// 8 loads = 32 edges in flight. Indices: 1 VMEM load of 32 idx by lane&31 + shfl
// broadcast. Clamped slots (past e1) all hit row e1-1 -> L1-absorbed. Epilogue:
// cross-group shfl_xor(16/32) reduce, lanes 0-15 write one uint4 each.
__global__ __launch_bounds__(256) void k_agg(const uint4* __restrict__ A,
                                             const int* __restrict__ row_ptr,
                                             const int* __restrict__ csr,
                                             const float* __restrict__ nd,
                                             uint4* __restrict__ Bh, int N) {
    int gtid = blockIdx.x * blockDim.x + threadIdx.x;
    int node = gtid >> 6;
    int lane = threadIdx.x & 63;
    if (node >= N) return;
    int e0 = row_ptr[node];
    int e1 = row_ptr[node + 1];
    int grp = lane >> 4;     // edge sub-slot within a 4-edge load row-group
    int l16 = lane & 15;     // 16-byte slot within 256B row
    float acc[8];
#pragma unroll
    for (int k = 0; k < 8; ++k) acc[k] = 0.0f;

    for (int base = e0; base < e1; base += 32) {
        int vl = csr[min(base + (lane & 31), e1 - 1)];   // lanes 0-31 hold 32 indices
        uint4 u[8];
#pragma unroll
        for (int j = 0; j < 8; ++j) {
            int idx = __shfl(vl, 4 * j + grp);
            u[j] = A[(size_t)idx * 16 + l16];
        }
#pragma unroll
        for (int j = 0; j < 8; ++j) {
            if (base + 4 * j + grp < e1) {
                __half2 h0 = *(__half2*)&u[j].x;
                __half2 h1 = *(__half2*)&u[j].y;
                __half2 h2 = *(__half2*)&u[j].z;
                __half2 h3 = *(__half2*)&u[j].w;
                float2 f0 = __half22float2(h0);
                float2 f1 = __half22float2(h1);
                float2 f2 = __half22float2(h2);
                float2 f3 = __half22float2(h3);
                acc[0] += f0.x; acc[1] += f0.y;
                acc[2] += f1.x; acc[3] += f1.y;
                acc[4] += f2.x; acc[5] += f2.y;
                acc[6] += f3.x; acc[7] += f3.y;
            }
        }
    }

#pragma unroll
    for (int k = 0; k < 8; ++k) {
        float v = acc[k];
        v += __shfl_xor(v, 16);
        v += __shfl_xor(v, 32);
        acc[k] = v;
    }

    if (grp == 0) {
        float s = nd[node];
        __half2 p0 = __floats2half2_rn(acc[0] * s, acc[1] * s);
        __half2 p1 = __floats2half2_rn(acc[2] * s, acc[3] * s);
        __half2 p2 = __floats2half2_rn(acc[4] * s, acc[5] * s);
        __half2 p3 = __floats2half2_rn(acc[6] * s, acc[7] * s);
        uint4 o;
        o.x = *(unsigned*)&p0;
        o.y = *(unsigned*)&p1;
        o.z = *(unsigned*)&p2;
        o.w = *(unsigned*)&p3;
        Bh[(size_t)node * 16 + l16] = o;
    }
}

// ---------------------------------------------------------------- GEMM on matrix cores (R15 transposed roles)
// X[node][f] = relu(Bin[node][:] @ W + b)[f], computed as D = Wt_frag * node_frag:
// A operand: lane=Wt[m=c*16+l16][k=q*32+quad*8+j]  (m = output feature)
// B operand: lane=Bin[node=blk*64+wave*16+l16][k=q*32+quad*8+j]
// C/D: col(l16)=node, row(quad*4+r)=feature -> thread owns node x 4 consecutive feats
// per c-tile: 8x half4 8B stores. SCALE_NS multiplies by ns[node] (layers 1-2).
template <bool SCALE_NS>
__global__ __launch_bounds__(256) void k_gemm_t(
    const _Float16* __restrict__ Bin, const _Float16* __restrict__ Wt,
    const float* __restrict__ bias, const float* __restrict__ ns,
    _Float16* __restrict__ Xout, int N) {
    int tid = threadIdx.x;
    int wave = tid >> 6;
    int lane = tid & 63;
    int quad = lane >> 4;
    int l16 = lane & 15;
    int node = blockIdx.x * 64 + wave * 16 + l16;

    half8 b[4];
#pragma unroll
    for (int q = 0; q < 4; ++q) {
        if (node < N) {
            b[q] = *(const half8*)&Bin[(size_t)node * DIM + q * 32 + quad * 8];
        } else {
            b[q] = half8{0, 0, 0, 0, 0, 0, 0, 0};
        }
    }

    floatx4 acc[8];
#pragma unroll
    for (int c = 0; c < 8; ++c) acc[c] = floatx4{0.f, 0.f, 0.f, 0.f};

#pragma unroll
    for (int c = 0; c < 8; ++c) {
#pragma unroll
        for (int q = 0; q < 4; ++q) {
            half8 a = *(const half8*)&Wt[(size_t)(c * 16 + l16) * DIM + q * 32 + quad * 8];
            acc[c] = __builtin_amdgcn_mfma_f32_16x16x32_f16(a, b[q], acc[c], 0, 0, 0);
        }
    }

    if (node < N) {
        float s = SCALE_NS ? ns[node] : 1.0f;
#pragma unroll
        for (int c = 0; c < 8; ++c) {
            float4 b4 = *(const float4*)&bias[c * 16 + quad * 4];
            half4 o;
            o[0] = (_Float16)(fmaxf(acc[c][0] + b4.x, 0.0f) * s);
            o[1] = (_Float16)(fmaxf(acc[c][1] + b4.y, 0.0f) * s);
            o[2] = (_Float16)(fmaxf(acc[c][2] + b4.z, 0.0f) * s);
            o[3] = (_Float16)(fmaxf(acc[c][3] + b4.w, 0.0f) * s);
            *(half4*)&Xout[(size_t)node * DIM + c * 16 + quad * 4] = o;
        }
    }
}

// ---------------------------------------------------------------- layer-3 GEMM fused with pooling
// Same MFMA body as k_gemm_t<false>, epilogue pools directly from fp32 acc.
#define PBINS 8
__global__ __launch_bounds__(256) void k_gemm_pool(
    const _Float16* __restrict__ Bin, const _Float16* __restrict__ Wt,
    const float* __restrict__ bias, const int* __restrict__ gid,
    float* __restrict__ gsum, int N) {
    __shared__ float lsum[PBINS * DIM];   // 4 KB
    int tid = threadIdx.x;
    for (int i = tid; i < PBINS * DIM; i += 256) lsum[i] = 0.0f;
    int wave = tid >> 6;
    int lane = tid & 63;
    int quad = lane >> 4;
    int l16 = lane & 15;
    int r0 = blockIdx.x * 64;
    int node = r0 + wave * 16 + l16;
    int nodec = min(node, N - 1);

    half8 b[4];
#pragma unroll
    for (int q = 0; q < 4; ++q) {
        if (node < N) {
            b[q] = *(const half8*)&Bin[(size_t)node * DIM + q * 32 + quad * 8];
        } else {
            b[q] = half8{0, 0, 0, 0, 0, 0, 0, 0};
        }
    }

    floatx4 acc[8];
#pragma unroll
    for (int c = 0; c < 8; ++c) acc[c] = floatx4{0.f, 0.f, 0.f, 0.f};
    __syncthreads();   // lsum zeros visible before any atomic below

#pragma unroll
    for (int c = 0; c < 8; ++c) {
#pragma unroll
        for (int q = 0; q < 4; ++q) {
            half8 a = *(const half8*)&Wt[(size_t)(c * 16 + l16) * DIM + q * 32 + quad * 8];
            acc[c] = __builtin_amdgcn_mfma_f32_16x16x32_f16(a, b[q], acc[c], 0, 0, 0);
        }
    }

    int g = gid[nodec];
    int g0b = gid[r0];                          // r0 < N for every block
    int gEb = gid[min(r0 + 63, N - 1)];
    bool ldsPath = (gEb - g0b) < PBINS;         // block spans < PBINS graphs
    int gF = __shfl(g, 0);                      // graph of wave-tile node 0
    int gL = __shfl(g, 15);                     // graph of wave-tile node 15
    bool uni = (gF == gL);                      // wave-uniform
    float valid = (node < N) ? 1.0f : 0.0f;     // zero padded-node contribution

#pragma unroll
    for (int c = 0; c < 8; ++c) {
        float4 b4 = *(const float4*)&bias[c * 16 + quad * 4];
        float bv[4] = {b4.x, b4.y, b4.z, b4.w};
#pragma unroll
        for (int r = 0; r < 4; ++r) {
            float v = fmaxf(acc[c][r] + bv[r], 0.0f) * valid;
            int f = c * 16 + quad * 4 + r;
            if (ldsPath) {
                if (uni) {
                    v += __shfl_xor(v, 1);
                    v += __shfl_xor(v, 2);
                    v += __shfl_xor(v, 4);
                    v += __shfl_xor(v, 8);      // sum over the 16 nodes of the tile
                    if (l16 == 0) atomicAdd(&lsum[(gF - g0b) * DIM + f], v);
                } else {
                    if (node < N) atomicAdd(&lsum[(g - g0b) * DIM + f], v);
                }
            } else {
                if (node < N) atomicAdd(&gsum[(size_t)g * DIM + f], v);
            }
        }
    }
    __syncthreads();
    if (ldsPath) {
        int ng = gEb - g0b + 1;
        for (int i = tid; i < ng * DIM; i += 256) {
            float sv = lsum[i];
            if (sv != 0.0f) atomicAdd(&gsum[(size_t)g0b * DIM + i], sv);
        }
    }
}

// ---------------------------------------------------------------- finalize (count via binary search)
__global__ void k_finalize(const float* __restrict__ gsum, const int* __restrict__ gid,
                           float* __restrict__ out, int N, int G) {
    int i = blockIdx.x * blockDim.x + threadIdx.x;
    if (i < G * DIM) {
        int g = i >> 7;
        int lo = 0, hi = N;                 // lower_bound(g)
        while (lo < hi) { int m = (lo + hi) >> 1; if (gid[m] < g) lo = m + 1; else hi = m; }
        int lo2 = lo, hi2 = N;              // lower_bound(g+1)
        while (lo2 < hi2) { int m = (lo2 + hi2) >> 1; if (gid[m] < g + 1) lo2 = m + 1; else hi2 = m; }
        float c = fmaxf((float)(lo2 - lo), 1.0f);
        out[i] = gsum[i] / c;
    }
}

// ---------------------------------------------------------------- launch
extern "C" void kernel_launch(void* const* d_in, const int* in_sizes, int n_in,
                              void* d_out, int out_size, void* d_ws, size_t ws_size,
                              hipStream_t stream) {
    const float* h   = (const float*)d_in[0];
    const int*   src = (const int*)d_in[1];
    const int*   dst = (const int*)d_in[2];
    const int*   gid = (const int*)d_in[3];
    const float* W1  = (const float*)d_in[4];
    const float* b1  = (const float*)d_in[5];
    const float* W2  = (const float*)d_in[6];
    const float* b2  = (const float*)d_in[7];
    const float* W3  = (const float*)d_in[8];
    const float* b3  = (const float*)d_in[9];

    const int N = in_sizes[0] / DIM;   // 50000
    const int E = in_sizes[1];         // 600000
    const int G = GRAPHS;
    float* out = (float*)d_out;

    char* ws = (char*)d_ws;
    size_t off = 0;
    auto alloc = [&](size_t bytes) -> void* {
        void* p = ws + off;
        off += (bytes + 255) & ~(size_t)255;
        return p;
    };
    const int nb = (N + 255) / 256;    // 196
    uint2* Ah0     = (uint2*)alloc((size_t)N * DIM * 2);  // fp16 gather operand (ping)
    uint2* Ah1     = (uint2*)alloc((size_t)N * DIM * 2);  // fp16 pong
    uint2* Bh      = (uint2*)alloc((size_t)N * DIM * 2);  // agg output (fp16)
    _Float16* Wt1  = (_Float16*)alloc((size_t)DIM * DIM * 2);
    _Float16* Wt2  = (_Float16*)alloc((size_t)DIM * DIM * 2);
    _Float16* Wt3  = (_Float16*)alloc((size_t)DIM * DIM * 2);
    float* ns      = (float*)alloc((size_t)N * 4);
    float* nd      = (float*)alloc((size_t)N * 4);
    int*   deg2    = (int*)alloc((size_t)2 * N * 4);      // degs | degd (contiguous, one memset)
    int*   row_ptr = (int*)alloc((size_t)(N + 1) * 4);
    int*   cursor  = (int*)alloc((size_t)N * 4);
    int*   csr     = (int*)alloc((size_t)E * 4);
    float* gsum    = (float*)alloc((size_t)G * DIM * 4);
    int*   bsum    = (int*)alloc((size_t)nb * 4);
    int*   degs = deg2;
    int*   degd = deg2 + N;

    int edgeBlocks = (E + 255) / 256;  // 2344

    // CSR build via global atomics (R19)
    hipMemsetAsync(deg2, 0, (size_t)2 * N * 4, stream);
    k_deg<<<edgeBlocks, 256, 0, stream>>>(src, dst, degs, degd, E);
    k_bsum<<<2 * nb, 256, 0, stream>>>(degs, degd, ns, nd, bsum, N);
    k_scan<<<nb, 256, 0, stream>>>(degd, bsum, row_ptr, cursor, gsum, N);
    k_fill<<<edgeBlocks, 256, 0, stream>>>(src, dst, cursor, csr, E);

    // Ah0 = fp16(h*ns) + weights -> fp16 transposed (single launch)
    int prepThreads = N * 32 + 3 * 16384;
    k_prep<<<(prepThreads + 255) / 256, 256, 0, stream>>>((const float4*)h, ns, Ah0,
                                                          W1, W2, W3, Wt1, Wt2, Wt3, N);

    int aggBlocks  = (N * 64 + 255) / 256;
    int gemmBlocks = (N + 63) / 64;

    // layer 1
    k_agg<<<aggBlocks, 256, 0, stream>>>((const uint4*)Ah0, row_ptr, csr, nd, (uint4*)Bh, N);
    k_gemm_t<true><<<gemmBlocks, 256, 0, stream>>>((const _Float16*)Bh, Wt1, b1, ns, (_Float16*)Ah1, N);
    // layer 2
    k_agg<<<aggBlocks, 256, 0, stream>>>((const uint4*)Ah1, row_ptr, csr, nd, (uint4*)Bh, N);
    k_gemm_t<true><<<gemmBlocks, 256, 0, stream>>>((const _Float16*)Bh, Wt2, b2, ns, (_Float16*)Ah0, N);
    // layer 3: agg + GEMM fused with pooling
    k_agg<<<aggBlocks, 256, 0, stream>>>((const uint4*)Ah0, row_ptr, csr, nd, (uint4*)Bh, N);
    k_gemm_pool<<<gemmBlocks, 256, 0, stream>>>((const _Float16*)Bh, Wt3, b3, gid, gsum, N);

    k_finalize<<<(G * DIM + 255) / 256, 256, 0, stream>>>(gsum, gid, out, N, G);
}

// Round 6
// 306.086 us; speedup vs baseline: 1.4043x; 1.1347x over previous
//
#include <hip/hip_runtime.h>
#include <hip/hip_fp16.h>

// GraphEmbedding2: 3-layer GCN (DGL GraphConv, norm='both') + per-graph mean pooling.
// N=50000 nodes, E=600000 edges, d=128, G=64 graphs.
// fp16 gather operands (R6); LDS-histogram degrees + LDS-cursor CSR fill (R5/R8);
// MFMA fp16-in/fp32-acc transposed roles (R9/R15); pool-fused layer 3 (R15);
// HIST_S=64 (R14); 32-edge-round agg (R17).
// R20: REVERT R19 atomic CSR build (FAILED +37us: k_deg alone 50.5us — scattered
// device-scope atomics ~24G/s on gfx950; LDS-histogram pipeline is cheaper. Measured.)
// Consolidation: k_prep folded into k_scan_write (both depend only on merge; -1
// dispatch, prep streaming overlaps cursor writes); fill2 lcur stage vectorized int4
// (12500 scalar loads/block -> 3125 int4); hist LDS->global writeback uint2.
// Reverted-for-cause: R7/R16 fusion (lost gather parallelism), R11 range passes,
// R13 HIST_S=32 (grid coverage), R18 quartered gather (cold-fill >= reuse),
// R19 global-atomic CSR build (atomic throughput wall).

#define DIM 128
#define GRAPHS 64

typedef _Float16 half8 __attribute__((ext_vector_type(8)));
typedef _Float16 half4 __attribute__((ext_vector_type(4)));
typedef float floatx4 __attribute__((ext_vector_type(4)));

// ---------------------------------------------------------------- degree histogram (LDS)
#define HIST_R 4
#define HIST_S 64
#define NPR 12500          // nodes per range (HIST_R * NPR = 50000)
#define LDSW (NPR / 2)     // 6250 u32 words, 25 KB LDS

__global__ __launch_bounds__(256) void k_hist(const int* __restrict__ src,
                                              const int* __restrict__ dst,
                                              unsigned* __restrict__ partial, int E) {
    __shared__ __align__(16) unsigned hist[LDSW];
    int b = blockIdx.x;
    int a = b / (HIST_R * HIST_S);       // 0: src, 1: dst
    int r = (b / HIST_S) % HIST_R;       // node range
    int s = b % HIST_S;                  // edge slice
    const int* arr = a ? dst : src;
    for (int i = threadIdx.x; i < LDSW; i += 256) hist[i] = 0;
    __syncthreads();
    int chunk = (E + HIST_S - 1) / HIST_S;
    int e0 = s * chunk;
    int e1 = min(e0 + chunk, E);
    unsigned base = (unsigned)(r * NPR);
    for (int i = e0 + threadIdx.x; i < e1; i += 256) {
        unsigned n = (unsigned)arr[i] - base;
        if (n < NPR) atomicAdd(&hist[n >> 1], 1u << ((n & 1) * 16));
    }
    __syncthreads();
    uint2* outp = (uint2*)(partial + ((size_t)(a * HIST_R + r) * HIST_S + s) * LDSW);
    const uint2* h2 = (const uint2*)hist;
    for (int i = threadIdx.x; i < LDSW / 2; i += 256) outp[i] = h2[i];
}

// ---------------------------------------------------------------- merge + block sums
// Blocks [0, nb): dst — nd, inc, per-256-node bsum. Blocks [nb, 2nb): src — ns.
__global__ __launch_bounds__(256) void k_hist_merge(const unsigned* __restrict__ partial,
                                                    float* __restrict__ ns,
                                                    float* __restrict__ nd,
                                                    int* __restrict__ inc,
                                                    int* __restrict__ bsum, int N) {
    __shared__ int sred[256];
    int nb = (N + 255) / 256;
    int isDst = (blockIdx.x < nb) ? 1 : 0;
    int cb = isDst ? blockIdx.x : blockIdx.x - nb;
    int n = cb * 256 + threadIdx.x;
    int deg = 0;
    if (n < N) {
        int a = isDst ? 1 : 0;
        int r = n / NPR;
        int w = (n % NPR) >> 1;
        int field = (n & 1) * 16;
        const unsigned* p = partial + ((size_t)(a * HIST_R + r) * HIST_S) * LDSW + w;
        unsigned sum = 0;
#pragma unroll
        for (int s = 0; s < HIST_S; ++s) sum += p[(size_t)s * LDSW];
        deg = (int)((sum >> field) & 0xFFFFu);
        float nrm = rsqrtf(fmaxf((float)deg, 1.0f));
        if (isDst) { nd[n] = nrm; inc[n] = deg; }
        else       { ns[n] = nrm; }
    }
    if (isDst) {
        sred[threadIdx.x] = deg;
        __syncthreads();
        for (int off = 128; off > 0; off >>= 1) {
            if (threadIdx.x < off) sred[threadIdx.x] += sred[threadIdx.x + off];
            __syncthreads();
        }
        if (threadIdx.x == 0) bsum[cb] = sred[0];
    }
}

// ---------------------------------------------------------------- scan_write + cursor + prep (folded)
// Blocks [0, nb): phase 0 block-sum scan -> phase A row_ptr scan -> phase B cursors;
// block 0 zeroes gsum. Blocks [nb, nb+prepBlocks): k_prep role — h->fp16(h*ns) and
// W1..3 -> fp16 transposed. Both roles depend only on k_hist_merge.
__global__ __launch_bounds__(256) void k_scan_prep(
    const int* __restrict__ inc, const int* __restrict__ bsum,
    const unsigned* __restrict__ partial, int* __restrict__ row_ptr,
    int* __restrict__ cur, float* __restrict__ gsum,
    const float4* __restrict__ h, const float* __restrict__ ns,
    uint2* __restrict__ A, const float* __restrict__ W1,
    const float* __restrict__ W2, const float* __restrict__ W3,
    _Float16* __restrict__ Wt1, _Float16* __restrict__ Wt2,
    _Float16* __restrict__ Wt3, int N) {
    __shared__ int sb[256];
    __shared__ int s[256];
    __shared__ int exs[256];
    int nb = (N + 255) / 256;
    int t = threadIdx.x;

    if (blockIdx.x >= nb) {
        // ---- prep role
        int i = (blockIdx.x - nb) * 256 + t;
        int nf4 = N * 32;
        if (i < nf4) {
            int n = i >> 5;
            float sc = ns[n];
            float4 v = h[i];
            __half2 p0 = __floats2half2_rn(v.x * sc, v.y * sc);
            __half2 p1 = __floats2half2_rn(v.z * sc, v.w * sc);
            uint2 o;
            o.x = *(unsigned*)&p0;
            o.y = *(unsigned*)&p1;
            A[i] = o;
        } else {
            int j = i - nf4;               // 0 .. 3*16384-1
            if (j < 3 * 16384) {
                int which = j >> 14;
                int local = j & 16383;
                int k = local >> 7;
                int n = local & 127;
                const float* W = (which == 0) ? W1 : (which == 1) ? W2 : W3;
                _Float16* Wt = (which == 0) ? Wt1 : (which == 1) ? Wt2 : Wt3;
                Wt[(size_t)n * DIM + k] = (_Float16)W[local];
            }
        }
        return;
    }

    // ---- scan role: phase 0 — exclusive-scan block sums
    int bv = (t < nb) ? bsum[t] : 0;
    sb[t] = bv;
    __syncthreads();
    for (int off = 1; off < 256; off <<= 1) {
        int u = (t >= off) ? sb[t - off] : 0;
        __syncthreads();
        sb[t] += u;
        __syncthreads();
    }
    int excl = sb[t] - bv;
    __syncthreads();
    sb[t] = excl;
    __syncthreads();
    int blockBase = sb[blockIdx.x];

    // phase A: local scan of inc
    int B = blockIdx.x * 256;
    int i = B + t;
    int v = (i < N) ? inc[i] : 0;
    s[t] = v;
    __syncthreads();
    for (int off = 1; off < 256; off <<= 1) {
        int u = (t >= off) ? s[t - off] : 0;
        __syncthreads();
        s[t] += u;
        __syncthreads();
    }
    int ex = blockBase + s[t] - v;  // global exclusive prefix
    exs[t] = ex;
    if (i < N) row_ptr[i] = ex;
    if (i == N - 1) row_ptr[N] = ex + v;
    if (blockIdx.x == 0) {
        for (int j = t; j < GRAPHS * DIM; j += 256) gsum[j] = 0.0f;
    }
    __syncthreads();

    // phase B: per-slice cursors
    if (t < 128) {
        int n0 = B + 2 * t;
        if (n0 < N) {
            int r = n0 / NPR;
            int w = (n0 % NPR) >> 1;
            const unsigned* p = partial + ((size_t)(HIST_R + r) * HIST_S) * LDSW + w;
            int run0 = exs[2 * t];
            int run1 = exs[2 * t + 1];
            int* c = cur + (size_t)r * HIST_S * NPR + 2 * w;
#pragma unroll
            for (int sl = 0; sl < HIST_S; ++sl) {
                c[(size_t)sl * NPR + 0] = run0;
                c[(size_t)sl * NPR + 1] = run1;
                unsigned hv = p[(size_t)sl * LDSW];
                run0 += (int)(hv & 0xFFFFu);
                run1 += (int)(hv >> 16);
            }
        }
    }
}

// ---------------------------------------------------------------- CSR fill (LDS cursors)
__global__ __launch_bounds__(256) void k_fill2(const int* __restrict__ src,
                                               const int* __restrict__ dst,
                                               const int* __restrict__ cur,
                                               int* __restrict__ csr, int E) {
    __shared__ __align__(16) int lcur[NPR];   // 50 KB
    int r = blockIdx.x / HIST_S;
    int s = blockIdx.x % HIST_S;
    const int4* cs4 = (const int4*)(cur + (size_t)(r * HIST_S + s) * NPR);
    int4* l4 = (int4*)lcur;
    for (int i = threadIdx.x; i < NPR / 4; i += 256) l4[i] = cs4[i];
    __syncthreads();
    int chunk = (E + HIST_S - 1) / HIST_S;
    int e0 = s * chunk;
    int e1 = min(e0 + chunk, E);
    unsigned base = (unsigned)(r * NPR);
    for (int i = e0 + threadIdx.x; i < e1; i += 256) {
        unsigned d = (unsigned)dst[i] - base;
        if (d < NPR) {
            int p = atomicAdd(&lcur[d], 1);   // LDS atomic
            csr[p] = src[i];
        }
    }
}

// ---------------------------------------------------------------- aggregation (R17 form)
// One wave per node (50K waves). 32-edge rounds: group = lane>>4 picks edge slot
// base+4j+grp, 16 lanes x 16B cover one 256B row -> 4 rows per load instruction,
// 8 loads = 32 edges in flight. Indices: 1 VMEM load of 32 idx by lane&31 + shfl
// broadcast. Clamped slots (past e1) all hit row e1-1 -> L1-absorbed. Epilogue:
// cross-group shfl_xor(16/32) reduce, lanes 0-15 write one uint4 each.
__global__ __launch_bounds__(256) void k_agg(const uint4* __restrict__ A,
                                             const int* __restrict__ row_ptr,
                                             const int* __restrict__ csr,
                                             const float* __restrict__ nd,
                                             uint4* __restrict__ Bh, int N) {
    int gtid = blockIdx.x * blockDim.x + threadIdx.x;
    int node = gtid >> 6;
    int lane = threadIdx.x & 63;
    if (node >= N) return;
    int e0 = row_ptr[node];
    int e1 = row_ptr[node + 1];
    int grp = lane >> 4;     // edge sub-slot within a 4-edge load row-group
    int l16 = lane & 15;     // 16-byte slot within 256B row
    float acc[8];
#pragma unroll
    for (int k = 0; k < 8; ++k) acc[k] = 0.0f;

    for (int base = e0; base < e1; base += 32) {
        int vl = csr[min(base + (lane & 31), e1 - 1)];   // lanes 0-31 hold 32 indices
        uint4 u[8];
#pragma unroll
        for (int j = 0; j < 8; ++j) {
            int idx = __shfl(vl, 4 * j + grp);
            u[j] = A[(size_t)idx * 16 + l16];
        }
#pragma unroll
        for (int j = 0; j < 8; ++j) {
            if (base + 4 * j + grp < e1) {
                __half2 h0 = *(__half2*)&u[j].x;
                __half2 h1 = *(__half2*)&u[j].y;
                __half2 h2 = *(__half2*)&u[j].z;
                __half2 h3 = *(__half2*)&u[j].w;
                float2 f0 = __half22float2(h0);
                float2 f1 = __half22float2(h1);
                float2 f2 = __half22float2(h2);
                float2 f3 = __half22float2(h3);
                acc[0] += f0.x; acc[1] += f0.y;
                acc[2] += f1.x; acc[3] += f1.y;
                acc[4] += f2.x; acc[5] += f2.y;
                acc[6] += f3.x; acc[7] += f3.y;
            }
        }
    }

#pragma unroll
    for (int k = 0; k < 8; ++k) {
        float v = acc[k];
        v += __shfl_xor(v, 16);
        v += __shfl_xor(v, 32);
        acc[k] = v;
    }

    if (grp == 0) {
        float s = nd[node];
        __half2 p0 = __floats2half2_rn(acc[0] * s, acc[1] * s);
        __half2 p1 = __floats2half2_rn(acc[2] * s, acc[3] * s);
        __half2 p2 = __floats2half2_rn(acc[4] * s, acc[5] * s);
        __half2 p3 = __floats2half2_rn(acc[6] * s, acc[7] * s);
        uint4 o;
        o.x = *(unsigned*)&p0;
        o.y = *(unsigned*)&p1;
        o.z = *(unsigned*)&p2;
        o.w = *(unsigned*)&p3;
        Bh[(size_t)node * 16 + l16] = o;
    }
}

// ---------------------------------------------------------------- GEMM on matrix cores (R15 transposed roles)
// X[node][f] = relu(Bin[node][:] @ W + b)[f], computed as D = Wt_frag * node_frag:
// A operand: lane=Wt[m=c*16+l16][k=q*32+quad*8+j]  (m = output feature)
// B operand: lane=Bin[node=blk*64+wave*16+l16][k=q*32+quad*8+j]
// C/D: col(l16)=node, row(quad*4+r)=feature -> thread owns node x 4 consecutive feats
// per c-tile: 8x half4 8B stores. SCALE_NS multiplies by ns[node] (layers 1-2).
template <bool SCALE_NS>
__global__ __launch_bounds__(256) void k_gemm_t(
    const _Float16* __restrict__ Bin, const _Float16* __restrict__ Wt,
    const float* __restrict__ bias, const float* __restrict__ ns,
    _Float16* __restrict__ Xout, int N) {
    int tid = threadIdx.x;
    int wave = tid >> 6;
    int lane = tid & 63;
    int quad = lane >> 4;
    int l16 = lane & 15;
    int node = blockIdx.x * 64 + wave * 16 + l16;

    half8 b[4];
#pragma unroll
    for (int q = 0; q < 4; ++q) {
        if (node < N) {
            b[q] = *(const half8*)&Bin[(size_t)node * DIM + q * 32 + quad * 8];
        } else {
            b[q] = half8{0, 0, 0, 0, 0, 0, 0, 0};
        }
    }

    floatx4 acc[8];
#pragma unroll
    for (int c = 0; c < 8; ++c) acc[c] = floatx4{0.f, 0.f, 0.f, 0.f};

#pragma unroll
    for (int c = 0; c < 8; ++c) {
#pragma unroll
        for (int q = 0; q < 4; ++q) {
            half8 a = *(const half8*)&Wt[(size_t)(c * 16 + l16) * DIM + q * 32 + quad * 8];
            acc[c] = __builtin_amdgcn_mfma_f32_16x16x32_f16(a, b[q], acc[c], 0, 0, 0);
        }
    }

    if (node < N) {
        float s = SCALE_NS ? ns[node] : 1.0f;
#pragma unroll
        for (int c = 0; c < 8; ++c) {
            float4 b4 = *(const float4*)&bias[c * 16 + quad * 4];
            half4 o;
            o[0] = (_Float16)(fmaxf(acc[c][0] + b4.x, 0.0f) * s);
            o[1] = (_Float16)(fmaxf(acc[c][1] + b4.y, 0.0f) * s);
            o[2] = (_Float16)(fmaxf(acc[c][2] + b4.z, 0.0f) * s);
            o[3] = (_Float16)(fmaxf(acc[c][3] + b4.w, 0.0f) * s);
            *(half4*)&Xout[(size_t)node * DIM + c * 16 + quad * 4] = o;
        }
    }
}

// ---------------------------------------------------------------- layer-3 GEMM fused with pooling
// Same MFMA body as k_gemm_t<false>, epilogue pools directly from fp32 acc.
#define PBINS 8
__global__ __launch_bounds__(256) void k_gemm_pool(
    const _Float16* __restrict__ Bin, const _Float16* __restrict__ Wt,
    const float* __restrict__ bias, const int* __restrict__ gid,
    float* __restrict__ gsum, int N) {
    __shared__ float lsum[PBINS * DIM];   // 4 KB
    int tid = threadIdx.x;
    for (int i = tid; i < PBINS * DIM; i += 256) lsum[i] = 0.0f;
    int wave = tid >> 6;
    int lane = tid & 63;
    int quad = lane >> 4;
    int l16 = lane & 15;
    int r0 = blockIdx.x * 64;
    int node = r0 + wave * 16 + l16;
    int nodec = min(node, N - 1);

    half8 b[4];
#pragma unroll
    for (int q = 0; q < 4; ++q) {
        if (node < N) {
            b[q] = *(const half8*)&Bin[(size_t)node * DIM + q * 32 + quad * 8];
        } else {
            b[q] = half8{0, 0, 0, 0, 0, 0, 0, 0};
        }
    }

    floatx4 acc[8];
#pragma unroll
    for (int c = 0; c < 8; ++c) acc[c] = floatx4{0.f, 0.f, 0.f, 0.f};
    __syncthreads();   // lsum zeros visible before any atomic below

#pragma unroll
    for (int c = 0; c < 8; ++c) {
#pragma unroll
        for (int q = 0; q < 4; ++q) {
            half8 a = *(const half8*)&Wt[(size_t)(c * 16 + l16) * DIM + q * 32 + quad * 8];
            acc[c] = __builtin_amdgcn_mfma_f32_16x16x32_f16(a, b[q], acc[c], 0, 0, 0);
        }
    }

    int g = gid[nodec];
    int g0b = gid[r0];                          // r0 < N for every block
    int gEb = gid[min(r0 + 63, N - 1)];
    bool ldsPath = (gEb - g0b) < PBINS;         // block spans < PBINS graphs
    int gF = __shfl(g, 0);                      // graph of wave-tile node 0
    int gL = __shfl(g, 15);                     // graph of wave-tile node 15
    bool uni = (gF == gL);                      // wave-uniform
    float valid = (node < N) ? 1.0f : 0.0f;     // zero padded-node contribution

#pragma unroll
    for (int c = 0; c < 8; ++c) {
        float4 b4 = *(const float4*)&bias[c * 16 + quad * 4];
        float bv[4] = {b4.x, b4.y, b4.z, b4.w};
#pragma unroll
        for (int r = 0; r < 4; ++r) {
            float v = fmaxf(acc[c][r] + bv[r], 0.0f) * valid;
            int f = c * 16 + quad * 4 + r;
            if (ldsPath) {
                if (uni) {
                    v += __shfl_xor(v, 1);
                    v += __shfl_xor(v, 2);
                    v += __shfl_xor(v, 4);
                    v += __shfl_xor(v, 8);      // sum over the 16 nodes of the tile
                    if (l16 == 0) atomicAdd(&lsum[(gF - g0b) * DIM + f], v);
                } else {
                    if (node < N) atomicAdd(&lsum[(g - g0b) * DIM + f], v);
                }
            } else {
                if (node < N) atomicAdd(&gsum[(size_t)g * DIM + f], v);
            }
        }
    }
    __syncthreads();
    if (ldsPath) {
        int ng = gEb - g0b + 1;
        for (int i = tid; i < ng * DIM; i += 256) {
            float sv = lsum[i];
            if (sv != 0.0f) atomicAdd(&gsum[(size_t)g0b * DIM + i], sv);
        }
    }
}

// ---------------------------------------------------------------- finalize (count via binary search)
__global__ void k_finalize(const float* __restrict__ gsum, const int* __restrict__ gid,
                           float* __restrict__ out, int N, int G) {
    int i = blockIdx.x * blockDim.x + threadIdx.x;
    if (i < G * DIM) {
        int g = i >> 7;
        int lo = 0, hi = N;                 // lower_bound(g)
        while (lo < hi) { int m = (lo + hi) >> 1; if (gid[m] < g) lo = m + 1; else hi = m; }
        int lo2 = lo, hi2 = N;              // lower_bound(g+1)
        while (lo2 < hi2) { int m = (lo2 + hi2) >> 1; if (gid[m] < g + 1) lo2 = m + 1; else hi2 = m; }
        float c = fmaxf((float)(lo2 - lo), 1.0f);
        out[i] = gsum[i] / c;
    }
}

// ---------------------------------------------------------------- launch
extern "C" void kernel_launch(void* const* d_in, const int* in_sizes, int n_in,
                              void* d_out, int out_size, void* d_ws, size_t ws_size,
                              hipStream_t stream) {
    const float* h   = (const float*)d_in[0];
    const int*   src = (const int*)d_in[1];
    const int*   dst = (const int*)d_in[2];
    const int*   gid = (const int*)d_in[3];
    const float* W1  = (const float*)d_in[4];
    const float* b1  = (const float*)d_in[5];
    const float* W2  = (const float*)d_in[6];
    const float* b2  = (const float*)d_in[7];
    const float* W3  = (const float*)d_in[8];
    const float* b3  = (const float*)d_in[9];

    const int N = in_sizes[0] / DIM;   // 50000
    const int E = in_sizes[1];         // 600000
    const int G = GRAPHS;
    float* out = (float*)d_out;

    char* ws = (char*)d_ws;
    size_t off = 0;
    auto alloc = [&](size_t bytes) -> void* {
        void* p = ws + off;
        off += (bytes + 255) & ~(size_t)255;
        return p;
    };
    const int nb = (N + 255) / 256;    // 196
    uint2* Ah0     = (uint2*)alloc((size_t)N * DIM * 2);  // fp16 gather operand (ping)
    uint2* Ah1     = (uint2*)alloc((size_t)N * DIM * 2);  // fp16 pong
    uint2* Bh      = (uint2*)alloc((size_t)N * DIM * 2);  // agg output (fp16)
    _Float16* Wt1  = (_Float16*)alloc((size_t)DIM * DIM * 2);
    _Float16* Wt2  = (_Float16*)alloc((size_t)DIM * DIM * 2);
    _Float16* Wt3  = (_Float16*)alloc((size_t)DIM * DIM * 2);
    float* ns      = (float*)alloc((size_t)N * 4);
    float* nd      = (float*)alloc((size_t)N * 4);
    int*   inc     = (int*)alloc((size_t)N * 4);
    unsigned* partial = (unsigned*)alloc((size_t)2 * HIST_R * HIST_S * LDSW * 4);  // 12.8 MB
    int*   cur     = (int*)alloc((size_t)HIST_R * HIST_S * NPR * 4);               // 12.8 MB
    int*   row_ptr = (int*)alloc((size_t)(N + 1) * 4);
    int*   csr     = (int*)alloc((size_t)E * 4);
    float* gsum    = (float*)alloc((size_t)G * DIM * 4);
    int*   bsum    = (int*)alloc((size_t)nb * 4);

    // degrees via LDS histograms (no global atomics)
    k_hist<<<2 * HIST_R * HIST_S, 256, 0, stream>>>(src, dst, partial, E);
    // merge -> ns/nd/inc + per-block sums
    k_hist_merge<<<2 * nb, 256, 0, stream>>>(partial, ns, nd, inc, bsum, N);
    // row_ptr + cursors + gsum zero + prep (folded: blocks >= nb convert h/weights)
    int prepBlocks = (N * 32 + 3 * 16384 + 255) / 256;   // 6442
    k_scan_prep<<<nb + prepBlocks, 256, 0, stream>>>(inc, bsum, partial, row_ptr, cur,
                                                     gsum, (const float4*)h, ns, Ah0,
                                                     W1, W2, W3, Wt1, Wt2, Wt3, N);
    k_fill2<<<HIST_R * HIST_S, 256, 0, stream>>>(src, dst, cur, csr, E);

    int aggBlocks  = (N * 64 + 255) / 256;
    int gemmBlocks = (N + 63) / 64;

    // layer 1
    k_agg<<<aggBlocks, 256, 0, stream>>>((const uint4*)Ah0, row_ptr, csr, nd, (uint4*)Bh, N);
    k_gemm_t<true><<<gemmBlocks, 256, 0, stream>>>((const _Float16*)Bh, Wt1, b1, ns, (_Float16*)Ah1, N);
    // layer 2
    k_agg<<<aggBlocks, 256, 0, stream>>>((const uint4*)Ah1, row_ptr, csr, nd, (uint4*)Bh, N);
    k_gemm_t<true><<<gemmBlocks, 256, 0, stream>>>((const _Float16*)Bh, Wt2, b2, ns, (_Float16*)Ah0, N);
    // layer 3: agg + GEMM fused with pooling
    k_agg<<<aggBlocks, 256, 0, stream>>>((const uint4*)Ah0, row_ptr, csr, nd, (uint4*)Bh, N);
    k_gemm_pool<<<gemmBlocks, 256, 0, stream>>>((const _Float16*)Bh, Wt3, b3, gid, gsum, N);

    k_finalize<<<(G * DIM + 255) / 256, 256, 0, stream>>>(gsum, gid, out, N, G);
}